// Round 1
// baseline (14643.344 us; speedup 1.0000x reference)
//
#include <hip/hip_runtime.h>

// ---------------- problem constants ----------------
#define BB 64      // batch
#define SS 512     // seq len
#define II 1024    // input dim (K for x@W)
#define HH 1024    // hidden
#define G4 4096    // 4*H fused gates
#define NWG_REC 64 // workgroups in recurrent kernel (must all be co-resident)

typedef unsigned short u16;
typedef unsigned int u32;
typedef unsigned long long u64;

typedef short s16x8 __attribute__((ext_vector_type(8)));   // 8 bf16 (4 VGPRs) MFMA A/B frag
typedef float f32x4 __attribute__((ext_vector_type(4)));   // MFMA C/D frag

typedef __attribute__((address_space(1))) const u32 as1_uint_t;
typedef __attribute__((address_space(3))) u32 as3_uint_t;

__device__ __forceinline__ u16 f2bf(float f) {   // RNE float->bf16
    u32 x = __float_as_uint(f);
    x += 0x7fffu + ((x >> 16) & 1u);
    return (u16)(x >> 16);
}
__device__ __forceinline__ float bf2f(u16 v) {
    return __uint_as_float(((u32)v) << 16);
}
__device__ __forceinline__ f32x4 mfma16(s16x8 a, s16x8 b, f32x4 c) {
    return __builtin_amdgcn_mfma_f32_16x16x32_bf16(a, b, c, 0, 0, 0);
}
__device__ __forceinline__ float sigm(float x) { return 1.f / (1.f + expf(-x)); }

// ---------------- prep: x fp32 -> bf16 ----------------
__global__ __launch_bounds__(256) void k_convert_x(const float* __restrict__ x,
                                                   u16* __restrict__ xb, int n4) {
    int i = blockIdx.x * 256 + threadIdx.x;
    int stride = gridDim.x * 256;
    const float4* xv = (const float4*)x;
    u64* ov = (u64*)xb;
    for (; i < n4; i += stride) {
        float4 v = xv[i];
        u64 o = (u64)f2bf(v.x) | ((u64)f2bf(v.y) << 16) |
                ((u64)f2bf(v.z) << 32) | ((u64)f2bf(v.w) << 48);
        ov[i] = o;
    }
}

// ---------------- prep: A[R][C] fp32 -> At[C][R] bf16 (tiled transpose) ----------------
__global__ __launch_bounds__(1024) void k_transpose_bf(const float* __restrict__ A,
                                                       u16* __restrict__ At, int R, int C) {
    __shared__ float tile[32][33];
    int cb = blockIdx.x * 32, rb = blockIdx.y * 32;
    int tx = threadIdx.x, ty = threadIdx.y;
    tile[ty][tx] = A[(size_t)(rb + ty) * C + cb + tx];
    __syncthreads();
    At[(size_t)(cb + ty) * R + rb + tx] = f2bf(tile[tx][ty]);
}

// ---------------- prep: zero h double-buffer + barrier counter ----------------
__global__ __launch_bounds__(256) void k_zero(u64* hb, u32* cnt) {
    int i = blockIdx.x * 256 + threadIdx.x;
    int stride = gridDim.x * 256;
    const int n = 2 * BB * HH * 2 / 8;   // bytes / 8
    for (; i < n; i += stride) hb[i] = 0ull;
    if (blockIdx.x == 0 && threadIdx.x == 0) *cnt = 0u;
}

// ---------------- phase 1: xW = x@W + b  (bf16 MFMA, fp32 out, row-permuted [s][b][4H]) --
// A: xb [32768][1024] bf16 row-major; B: Wt [4096][1024] bf16 (k contiguous)
template <bool XW32>
__global__ __launch_bounds__(256) void k_gemm_xw(const u16* __restrict__ Abf,
                                                 const u16* __restrict__ Bt,
                                                 const float* __restrict__ bias,
                                                 void* __restrict__ xw) {
    __shared__ u16 As[128 * 32];
    __shared__ u16 Bs[128 * 32];
    int bid = blockIdx.x;
    // XCD-chunked swizzle: XCD x gets contiguous work ids -> 4 B-panels stay in its L2
    int wid = (bid & 7) * 1024 + (bid >> 3);
    int mt = wid & 255, nt = wid >> 8;
    size_t rb = (size_t)mt * 128;
    int cb = nt * 128;
    int tid = threadIdx.x;
    int w = tid >> 6, l = tid & 63;
    int lr = l >> 4, lc = l & 15;
    int wr = (w >> 1) * 64, wc = (w & 1) * 64;
    f32x4 acc[4][4] = {};
    for (int kb = 0; kb < II; kb += 32) {
        __syncthreads();
#pragma unroll
        for (int q = 0; q < 2; ++q) {
            int bo = q * 4096 + w * 1024 + l * 16;      // byte offset in 8KB tile
            int row = bo >> 6;                          // /64B per row
            int off = (bo & 63) >> 1;                   // elem offset in row
            const u16* srcA = Abf + (rb + row) * II + kb + off;
            __builtin_amdgcn_global_load_lds((as1_uint_t*)srcA,
                (as3_uint_t*)((char*)As + q * 4096 + w * 1024), 16, 0, 0);
            const u16* srcB = Bt + (size_t)(cb + row) * II + kb + off;
            __builtin_amdgcn_global_load_lds((as1_uint_t*)srcB,
                (as3_uint_t*)((char*)Bs + q * 4096 + w * 1024), 16, 0, 0);
        }
        __syncthreads();
        s16x8 af[4], bf[4];
#pragma unroll
        for (int m = 0; m < 4; ++m)
            af[m] = *(const s16x8*)(As + (wr + m * 16 + lc) * 32 + lr * 8);
#pragma unroll
        for (int n = 0; n < 4; ++n)
            bf[n] = *(const s16x8*)(Bs + (wc + n * 16 + lc) * 32 + lr * 8);
#pragma unroll
        for (int m = 0; m < 4; ++m)
#pragma unroll
            for (int n = 0; n < 4; ++n)
                acc[m][n] = mfma16(af[m], bf[n], acc[m][n]);
    }
    // epilogue: +bias, permuted store row (b*512+s) -> (s*64+b)
    float bv[4];
#pragma unroll
    for (int n = 0; n < 4; ++n) bv[n] = bias[cb + wc + n * 16 + lc];
#pragma unroll
    for (int m = 0; m < 4; ++m) {
#pragma unroll
        for (int r = 0; r < 4; ++r) {
            size_t g = rb + wr + m * 16 + lr * 4 + r;       // global row b*512+s
            size_t srow = ((g & 511) << 6) | (g >> 9);      // s*64 + b
#pragma unroll
            for (int n = 0; n < 4; ++n) {
                float v = acc[m][n][r] + bv[n];
                size_t idx = srow * G4 + cb + wc + n * 16 + lc;
                if (XW32) ((float*)xw)[idx] = v;
                else      ((u16*)xw)[idx] = f2bf(v);
            }
        }
    }
}

// ---------------- phase 2: persistent recurrent kernel -------------------------------
// MODE 0: xw fp32 precomputed; MODE 1: xw bf16 precomputed; MODE 2: fused x_t@W in-loop
// 64 WGs x 256 thr. WG j owns h-cols [j*16, j*16+16); wave w owns batch rows [16w,16w+16).
// Per lane: acc[g] C-frag -> (row=(l>>4)*4+r, col=l&15) identical for all 4 gates, so
// c lives in registers for the whole sequence.
template <int MODE>
__global__ __launch_bounds__(256) void k_lstm(const u16* __restrict__ Ut,
                                              const u16* __restrict__ Wt,
                                              const u16* __restrict__ xb,
                                              const float* __restrict__ bias,
                                              const void* __restrict__ xw,
                                              u16* hb, u32* cnt,
                                              float* __restrict__ out) {
    __shared__ u16 hs[64][16];
    int j = blockIdx.x;
    int tid = threadIdx.x;
    int w = tid >> 6, l = tid & 63;
    int lr = l >> 4, lc = l & 15;
    int rowbase = w * 16;
    int col = j * 16 + lc;
    float c[4] = {0.f, 0.f, 0.f, 0.f};
    const float* xwf = (const float*)xw;
    const u16* xwh = (const u16*)xw;

    for (int t = 0; t < SS; ++t) {
        f32x4 acc[4];
        if (MODE == 2) {
#pragma unroll
            for (int g = 0; g < 4; ++g) {
                float bv = bias[g * HH + col];
#pragma unroll
                for (int r = 0; r < 4; ++r) acc[g][r] = bv;
            }
            // x_t @ W part (cached loads; xb row for batch b is at (b*SS+t)*II)
            const u16* xrow = xb + ((size_t)(rowbase + lc) * SS + t) * II;
#pragma unroll 4
            for (int kk = 0; kk < 32; ++kk) {
                int k0 = kk * 32 + lr * 8;
                s16x8 av = *(const s16x8*)(xrow + k0);
#pragma unroll
                for (int g = 0; g < 4; ++g) {
                    s16x8 bv = *(const s16x8*)(Wt + (size_t)(g * HH + col) * II + k0);
                    acc[g] = mfma16(av, bv, acc[g]);
                }
            }
        } else {
            size_t base = (size_t)t * BB * G4;
#pragma unroll
            for (int g = 0; g < 4; ++g)
#pragma unroll
                for (int r = 0; r < 4; ++r) {
                    size_t idx = base + (size_t)(rowbase + lr * 4 + r) * G4 + g * HH + col;
                    acc[g][r] = (MODE == 0) ? xwf[idx] : bf2f(xwh[idx]);
                }
        }
        // h_{t-1} @ U  (h read coherently: other XCDs wrote it write-through)
        const u16* hrd = hb + (size_t)(t & 1) * BB * HH;
        const u64* arow = (const u64*)(hrd + (size_t)(rowbase + lc) * HH);
#pragma unroll 4
        for (int kk = 0; kk < 32; ++kk) {
            int k0 = kk * 32 + lr * 8;
            u64 a0 = __hip_atomic_load(arow + (k0 >> 2), __ATOMIC_RELAXED, __HIP_MEMORY_SCOPE_AGENT);
            u64 a1 = __hip_atomic_load(arow + (k0 >> 2) + 1, __ATOMIC_RELAXED, __HIP_MEMORY_SCOPE_AGENT);
            union { u64 u[2]; s16x8 v; } au;
            au.u[0] = a0; au.u[1] = a1;
#pragma unroll
            for (int g = 0; g < 4; ++g) {
                s16x8 bv = *(const s16x8*)(Ut + (size_t)(g * HH + col) * II + k0);
                acc[g] = mfma16(au.v, bv, acc[g]);
            }
        }
        // activations, cell update, outputs
        u16* hwr = hb + (size_t)((t + 1) & 1) * BB * HH;
#pragma unroll
        for (int r = 0; r < 4; ++r) {
            int row = rowbase + lr * 4 + r;
            float i_ = sigm(acc[0][r]);
            float f_ = sigm(acc[1][r]);
            float g_ = tanhf(acc[2][r]);
            float o_ = sigm(acc[3][r]);
            c[r] = f_ * c[r] + i_ * g_;
            float h_ = o_ * tanhf(c[r]);
            out[(size_t)row * (SS * HH) + (size_t)t * HH + col] = h_;
            if (t == SS - 1) {
                out[(size_t)BB * SS * HH + (size_t)row * HH + col] = h_;                  // h_t
                out[(size_t)BB * SS * HH + BB * HH + (size_t)row * HH + col] = c[r];      // c_t
            }
            hs[row][lc] = f2bf(h_);
        }
        __syncthreads();
        {   // coalesced coherent store of this WG's h slice (64 rows x 16 cols bf16)
            int rr = tid >> 2, cc = (tid & 3) * 4;
            u64 v = *(const u64*)&hs[rr][cc];
            __hip_atomic_store((u64*)(hwr + (size_t)rr * HH + j * 16 + cc), v,
                               __ATOMIC_RELAXED, __HIP_MEMORY_SCOPE_AGENT);
        }
        __syncthreads();
        if (t < SS - 1) {   // monotonic-counter grid barrier (all 64 WGs co-resident)
            if (tid == 0) {
                __hip_atomic_fetch_add(cnt, 1u, __ATOMIC_RELEASE, __HIP_MEMORY_SCOPE_AGENT);
                u32 target = (u32)(t + 1) * NWG_REC;
                while (__hip_atomic_load(cnt, __ATOMIC_ACQUIRE, __HIP_MEMORY_SCOPE_AGENT) < target)
                    __builtin_amdgcn_s_sleep(2);
            }
            __syncthreads();
        }
    }
}

// ---------------- host launch ----------------
extern "C" void kernel_launch(void* const* d_in, const int* in_sizes, int n_in,
                              void* d_out, int out_size, void* d_ws, size_t ws_size,
                              hipStream_t stream) {
    const float* x = (const float*)d_in[0];
    const float* W = (const float*)d_in[1];
    const float* U = (const float*)d_in[2];
    const float* b = (const float*)d_in[3];
    float* out = (float*)d_out;

    size_t xb_b  = (size_t)BB * SS * II * 2;   // 64 MiB
    size_t wt_b  = (size_t)G4 * II * 2;        // 8 MiB each
    size_t hb_b  = (size_t)2 * BB * HH * 2;    // 256 KiB
    size_t xw32_b = (size_t)BB * SS * G4 * 4;  // 512 MiB
    size_t xw16_b = xw32_b / 2;
    size_t base = xb_b + 2 * wt_b;

    int mode;
    if (base + xw32_b + hb_b + 256 <= ws_size)      mode = 0;
    else if (base + xw16_b + hb_b + 256 <= ws_size) mode = 1;
    else                                            mode = 2;

    char* p = (char*)d_ws;
    u16* xb = (u16*)p;
    u16* Wt = (u16*)(p + xb_b);
    u16* Ut = (u16*)(p + xb_b + wt_b);
    char* q = p + base;
    void* xw = nullptr;
    if (mode == 0) { xw = q; q += xw32_b; }
    else if (mode == 1) { xw = q; q += xw16_b; }
    u16* hb = (u16*)q; q += hb_b;
    u32* cnt = (u32*)q;

    k_convert_x<<<2048, 256, 0, stream>>>(x, xb, BB * SS * II / 4);
    k_transpose_bf<<<dim3(G4 / 32, II / 32), dim3(32, 32), 0, stream>>>(W, Wt, II, G4);
    k_transpose_bf<<<dim3(G4 / 32, II / 32), dim3(32, 32), 0, stream>>>(U, Ut, II, G4);
    k_zero<<<64, 256, 0, stream>>>((u64*)hb, cnt);

    if (mode == 0) {
        k_gemm_xw<true><<<8192, 256, 0, stream>>>(xb, Wt, b, xw);
        k_lstm<0><<<NWG_REC, 256, 0, stream>>>(Ut, Wt, xb, b, xw, hb, cnt, out);
    } else if (mode == 1) {
        k_gemm_xw<false><<<8192, 256, 0, stream>>>(xb, Wt, b, xw);
        k_lstm<1><<<NWG_REC, 256, 0, stream>>>(Ut, Wt, xb, b, xw, hb, cnt, out);
    } else {
        k_lstm<2><<<NWG_REC, 256, 0, stream>>>(Ut, Wt, xb, b, nullptr, hb, cnt, out);
    }
}

// Round 2
// 6737.617 us; speedup vs baseline: 2.1734x; 2.1734x over previous
//
#include <hip/hip_runtime.h>

// ---------------- problem constants ----------------
#define BB 64      // batch
#define SS 512     // seq len
#define II 1024    // input dim (K for x@W)
#define HH 1024    // hidden
#define G4 4096    // 4*H fused gates
#define NWG_REC 64 // workgroups in recurrent kernel (must all be co-resident)

typedef unsigned short u16;
typedef unsigned int u32;
typedef unsigned long long u64;

typedef short s16x8 __attribute__((ext_vector_type(8)));   // 8 bf16 (4 VGPRs) MFMA A/B frag
typedef float f32x4 __attribute__((ext_vector_type(4)));   // MFMA C/D frag

typedef __attribute__((address_space(1))) const u32 as1_uint_t;
typedef __attribute__((address_space(3))) u32 as3_uint_t;

__device__ __forceinline__ u16 f2bf(float f) {   // RNE float->bf16
    u32 x = __float_as_uint(f);
    x += 0x7fffu + ((x >> 16) & 1u);
    return (u16)(x >> 16);
}
__device__ __forceinline__ float bf2f(u16 v) {
    return __uint_as_float(((u32)v) << 16);
}
__device__ __forceinline__ f32x4 mfma16(s16x8 a, s16x8 b, f32x4 c) {
    return __builtin_amdgcn_mfma_f32_16x16x32_bf16(a, b, c, 0, 0, 0);
}
__device__ __forceinline__ float fsigm(float x) { return 1.f / (1.f + __expf(-x)); }
__device__ __forceinline__ float ftanh(float x) {
    float e = __expf(2.f * x);
    return (e - 1.f) / (e + 1.f);
}

// ---------------- prep: x fp32 -> bf16 ----------------
__global__ __launch_bounds__(256) void k_convert_x(const float* __restrict__ x,
                                                   u16* __restrict__ xb, int n4) {
    int i = blockIdx.x * 256 + threadIdx.x;
    int stride = gridDim.x * 256;
    const float4* xv = (const float4*)x;
    u64* ov = (u64*)xb;
    for (; i < n4; i += stride) {
        float4 v = xv[i];
        u64 o = (u64)f2bf(v.x) | ((u64)f2bf(v.y) << 16) |
                ((u64)f2bf(v.z) << 32) | ((u64)f2bf(v.w) << 48);
        ov[i] = o;
    }
}

// ---------------- prep: A[R][C] fp32 -> At[C][R] bf16 (tiled transpose) ----------------
__global__ __launch_bounds__(1024) void k_transpose_bf(const float* __restrict__ A,
                                                       u16* __restrict__ At, int R, int C) {
    __shared__ float tile[32][33];
    int cb = blockIdx.x * 32, rb = blockIdx.y * 32;
    int tx = threadIdx.x, ty = threadIdx.y;
    tile[ty][tx] = A[(size_t)(rb + ty) * C + cb + tx];
    __syncthreads();
    At[(size_t)(cb + ty) * R + rb + tx] = f2bf(tile[tx][ty]);
}

// ---------------- prep: zero h double-buffer + barrier counter ----------------
__global__ __launch_bounds__(256) void k_zero(u64* hb, u32* cnt) {
    int i = blockIdx.x * 256 + threadIdx.x;
    int stride = gridDim.x * 256;
    const int n = 2 * BB * HH * 2 / 8;   // bytes / 8
    for (; i < n; i += stride) hb[i] = 0ull;
    if (blockIdx.x == 0 && threadIdx.x == 0) *cnt = 0u;
}

// ---------------- phase 1: xW = x@W + b  (bf16 MFMA, fp32 out, row-permuted [s][b][4H]) --
// A: xb [32768][1024] bf16 row-major; B: Wt [4096][1024] bf16 (k contiguous)
template <bool XW32>
__global__ __launch_bounds__(256) void k_gemm_xw(const u16* __restrict__ Abf,
                                                 const u16* __restrict__ Bt,
                                                 const float* __restrict__ bias,
                                                 void* __restrict__ xw) {
    __shared__ u16 As[128 * 32];
    __shared__ u16 Bs[128 * 32];
    int bid = blockIdx.x;
    int wid = (bid & 7) * 1024 + (bid >> 3);   // XCD-chunked swizzle
    int mt = wid & 255, nt = wid >> 8;
    size_t rb = (size_t)mt * 128;
    int cb = nt * 128;
    int tid = threadIdx.x;
    int w = tid >> 6, l = tid & 63;
    int lr = l >> 4, lc = l & 15;
    int wr = (w >> 1) * 64, wc = (w & 1) * 64;
    f32x4 acc[4][4] = {};
    for (int kb = 0; kb < II; kb += 32) {
        __syncthreads();
#pragma unroll
        for (int q = 0; q < 2; ++q) {
            int bo = q * 4096 + w * 1024 + l * 16;
            int row = bo >> 6;
            int off = (bo & 63) >> 1;
            const u16* srcA = Abf + (rb + row) * II + kb + off;
            __builtin_amdgcn_global_load_lds((as1_uint_t*)srcA,
                (as3_uint_t*)((char*)As + q * 4096 + w * 1024), 16, 0, 0);
            const u16* srcB = Bt + (size_t)(cb + row) * II + kb + off;
            __builtin_amdgcn_global_load_lds((as1_uint_t*)srcB,
                (as3_uint_t*)((char*)Bs + q * 4096 + w * 1024), 16, 0, 0);
        }
        __syncthreads();
        s16x8 af[4], bf[4];
#pragma unroll
        for (int m = 0; m < 4; ++m)
            af[m] = *(const s16x8*)(As + (wr + m * 16 + lc) * 32 + lr * 8);
#pragma unroll
        for (int n = 0; n < 4; ++n)
            bf[n] = *(const s16x8*)(Bs + (wc + n * 16 + lc) * 32 + lr * 8);
#pragma unroll
        for (int m = 0; m < 4; ++m)
#pragma unroll
            for (int n = 0; n < 4; ++n)
                acc[m][n] = mfma16(af[m], bf[n], acc[m][n]);
    }
    float bv[4];
#pragma unroll
    for (int n = 0; n < 4; ++n) bv[n] = bias[cb + wc + n * 16 + lc];
#pragma unroll
    for (int m = 0; m < 4; ++m) {
#pragma unroll
        for (int r = 0; r < 4; ++r) {
            size_t g = rb + wr + m * 16 + lr * 4 + r;       // global row b*512+s
            size_t srow = ((g & 511) << 6) | (g >> 9);      // s*64 + b
#pragma unroll
            for (int n = 0; n < 4; ++n) {
                float v = acc[m][n][r] + bv[n];
                size_t idx = srow * G4 + cb + wc + n * 16 + lc;
                if (XW32) ((float*)xw)[idx] = v;
                else      ((u16*)xw)[idx] = f2bf(v);
            }
        }
    }
}

// ---------------- phase 2: persistent recurrent kernel -------------------------------
// 64 WGs x 256 thr, 1 WG/CU. WG j owns h-cols [j*16, j*16+16) x 4 gates; wave w owns
// batch rows [16w,16w+16). U slice (128 KB) staged in LDS ONCE in MFMA B-frag chunk
// order [kk][g][lr][lc][8] -> every ds_read_b128 is a contiguous 1024B wave access.
// h exchange: relaxed agent atomic stores (write-through to LLC) + RELEASE counter add;
// consumers spin RELAXED then one ACQUIRE agent fence per wave per step (single
// buffer_inv), then plain pipelined vector loads of h. xw(t+1) prefetched to registers.
template <bool XW32>
__global__ __launch_bounds__(256, 1) void k_lstm2(const u16* __restrict__ Ut,
                                                  const void* __restrict__ xw,
                                                  u16* hb, u32* cnt,
                                                  float* __restrict__ out) {
    __shared__ u16 Us[8192 * 8];   // 128 KB: chunk ch=((kk*4+g)*4+lr)*16+lc, 8 bf16 each
    __shared__ u16 hs[64][16];
    const int j = blockIdx.x;
    const int tid = threadIdx.x;
    const int w = tid >> 6, l = tid & 63;
    const int lr = l >> 4, lc = l & 15;
    const int rowbase = w * 16;
    const int col = j * 16 + lc;

    // ---- stage U slice into LDS (one-time) ----
    for (int i = 0; i < 32; ++i) {
        int ch = tid + (i << 8);
        int lc2 = ch & 15, lr2 = (ch >> 4) & 3, g2 = (ch >> 6) & 3, kk2 = ch >> 8;
        const u16* src = Ut + (size_t)(g2 * HH + j * 16 + lc2) * II + kk2 * 32 + lr2 * 8;
        *(s16x8*)(Us + (size_t)ch * 8) = *(const s16x8*)src;
    }

    float cc[4] = {0.f, 0.f, 0.f, 0.f};
    const float* xwf = (const float*)xw;
    const u16* xwh = (const u16*)xw;
    const size_t xwbase = (size_t)(rowbase + lr * 4) * G4 + col;

    float cur[16], nxt[16];
#pragma unroll
    for (int g = 0; g < 4; ++g)
#pragma unroll
        for (int r = 0; r < 4; ++r) {
            size_t idx = xwbase + (size_t)r * G4 + (size_t)g * HH;
            cur[g * 4 + r] = XW32 ? xwf[idx] : bf2f(xwh[idx]);
        }
    __syncthreads();   // Us ready

    for (int t = 0; t < SS; ++t) {
        // prefetch xw(t+1) into registers (hides HBM latency under this step)
        if (t + 1 < SS) {
            size_t base = (size_t)(t + 1) * (BB * G4) + xwbase;
#pragma unroll
            for (int g = 0; g < 4; ++g)
#pragma unroll
                for (int r = 0; r < 4; ++r) {
                    size_t idx = base + (size_t)r * G4 + (size_t)g * HH;
                    nxt[g * 4 + r] = XW32 ? xwf[idx] : bf2f(xwh[idx]);
                }
        }
        // 8 accumulation chains (even/odd kk) — 1 wave/SIMD, need ILP vs MFMA latency
        f32x4 acc[4], acd[4];
#pragma unroll
        for (int g = 0; g < 4; ++g)
#pragma unroll
            for (int r = 0; r < 4; ++r) { acc[g][r] = cur[g * 4 + r]; acd[g][r] = 0.f; }

        const u16* hrow = hb + (size_t)(t & 1) * (BB * HH) +
                          (size_t)(rowbase + lc) * HH + lr * 8;
#pragma unroll
        for (int kb = 0; kb < 4; ++kb) {
            s16x8 av[8];
#pragma unroll
            for (int u = 0; u < 8; ++u)
                av[u] = *(const s16x8*)(hrow + (kb * 8 + u) * 32);
#pragma unroll
            for (int u = 0; u < 8; ++u) {
                const int kk = kb * 8 + u;
#pragma unroll
                for (int g = 0; g < 4; ++g) {
                    const s16x8 bv = *(const s16x8*)(Us + (size_t)((((kk * 4 + g) * 4 + lr) * 16 + lc)) * 8);
                    if (u & 1) acd[g] = mfma16(av[u], bv, acd[g]);
                    else       acc[g] = mfma16(av[u], bv, acc[g]);
                }
            }
        }
        // activations, cell update, outputs
        u16* hwr = hb + (size_t)((t + 1) & 1) * (BB * HH);
#pragma unroll
        for (int r = 0; r < 4; ++r) {
            int row = rowbase + lr * 4 + r;
            float i_ = fsigm(acc[0][r] + acd[0][r]);
            float f_ = fsigm(acc[1][r] + acd[1][r]);
            float g_ = ftanh(acc[2][r] + acd[2][r]);
            float o_ = fsigm(acc[3][r] + acd[3][r]);
            cc[r] = f_ * cc[r] + i_ * g_;
            float h_ = o_ * ftanh(cc[r]);
            out[(size_t)row * (SS * HH) + (size_t)t * HH + col] = h_;
            if (t == SS - 1) {
                out[(size_t)(BB * SS * HH) + (size_t)row * HH + col] = h_;                 // h_t
                out[(size_t)(BB * SS * HH + BB * HH) + (size_t)row * HH + col] = cc[r];    // c_t
            }
            hs[row][lc] = f2bf(h_);
        }
        __syncthreads();
        {   // coalesced write-through of this WG's h slice (64 rows x 16 cols bf16)
            int rr = tid >> 2, cw = (tid & 3) * 4;
            u64 v = *(const u64*)&hs[rr][cw];
            __hip_atomic_store((u64*)(hwr + (size_t)rr * HH + j * 16 + cw), v,
                               __ATOMIC_RELAXED, __HIP_MEMORY_SCOPE_AGENT);
        }
        if (t < SS - 1) {
            __syncthreads();   // drains vmcnt -> h stores acked (write-through done)
            if (tid == 0) {
                __hip_atomic_fetch_add(cnt, 1u, __ATOMIC_RELEASE, __HIP_MEMORY_SCOPE_AGENT);
                u32 target = (u32)(t + 1) * NWG_REC;
                while (__hip_atomic_load(cnt, __ATOMIC_RELAXED, __HIP_MEMORY_SCOPE_AGENT) < target)
                    __builtin_amdgcn_s_sleep(1);
            }
            __syncthreads();
            // one invalidate per wave per step: subsequent plain h loads read LLC
            __builtin_amdgcn_fence(__ATOMIC_ACQUIRE, "agent");
        }
#pragma unroll
        for (int q = 0; q < 16; ++q) cur[q] = nxt[q];
    }
}

// ---------------- host launch ----------------
extern "C" void kernel_launch(void* const* d_in, const int* in_sizes, int n_in,
                              void* d_out, int out_size, void* d_ws, size_t ws_size,
                              hipStream_t stream) {
    const float* x = (const float*)d_in[0];
    const float* W = (const float*)d_in[1];
    const float* U = (const float*)d_in[2];
    const float* b = (const float*)d_in[3];
    float* out = (float*)d_out;

    size_t xb_b  = (size_t)BB * SS * II * 2;   // 64 MiB
    size_t wt_b  = (size_t)G4 * II * 2;        // 8 MiB each
    size_t hb_b  = (size_t)2 * BB * HH * 2;    // 256 KiB
    size_t xw32_b = (size_t)BB * SS * G4 * 4;  // 512 MiB
    size_t xw16_b = xw32_b / 2;
    size_t base = xb_b + 2 * wt_b;

    int mode = (base + xw32_b + hb_b + 256 <= ws_size) ? 0 : 1;

    char* p = (char*)d_ws;
    u16* xb = (u16*)p;
    u16* Wt = (u16*)(p + xb_b);
    u16* Ut = (u16*)(p + xb_b + wt_b);
    char* q = p + base;
    void* xw = (void*)q;
    q += (mode == 0) ? xw32_b : xw16_b;
    u16* hb = (u16*)q; q += hb_b;
    u32* cnt = (u32*)q;

    k_convert_x<<<2048, 256, 0, stream>>>(x, xb, BB * SS * II / 4);
    k_transpose_bf<<<dim3(G4 / 32, II / 32), dim3(32, 32), 0, stream>>>(W, Wt, II, G4);
    k_transpose_bf<<<dim3(G4 / 32, II / 32), dim3(32, 32), 0, stream>>>(U, Ut, II, G4);
    k_zero<<<64, 256, 0, stream>>>((u64*)hb, cnt);

    if (mode == 0) {
        k_gemm_xw<true><<<8192, 256, 0, stream>>>(xb, Wt, b, xw);
        k_lstm2<true><<<NWG_REC, 256, 0, stream>>>(Ut, xw, hb, cnt, out);
    } else {
        k_gemm_xw<false><<<8192, 256, 0, stream>>>(xb, Wt, b, xw);
        k_lstm2<false><<<NWG_REC, 256, 0, stream>>>(Ut, xw, hb, cnt, out);
    }
}

// Round 3
// 5686.762 us; speedup vs baseline: 2.5750x; 1.1848x over previous
//
#include <hip/hip_runtime.h>

// ---------------- problem constants ----------------
#define BB 64      // batch
#define SS 512     // seq len
#define II 1024    // input dim (K for x@W)
#define HH 1024    // hidden
#define G4 4096    // 4*H fused gates
#define NWG_REC 64 // workgroups in recurrent kernel (must all be co-resident)

typedef unsigned short u16;
typedef unsigned int u32;
typedef unsigned long long u64;

typedef short s16x8 __attribute__((ext_vector_type(8)));   // 8 bf16 (4 VGPRs) MFMA A/B frag
typedef float f32x4 __attribute__((ext_vector_type(4)));   // MFMA C/D frag

typedef __attribute__((address_space(1))) const u32 as1_uint_t;
typedef __attribute__((address_space(3))) u32 as3_uint_t;

__device__ __forceinline__ u16 f2bf(float f) {   // RNE float->bf16
    u32 x = __float_as_uint(f);
    x += 0x7fffu + ((x >> 16) & 1u);
    return (u16)(x >> 16);
}
__device__ __forceinline__ float bf2f(u16 v) {
    return __uint_as_float(((u32)v) << 16);
}
__device__ __forceinline__ f32x4 mfma16(s16x8 a, s16x8 b, f32x4 c) {
    return __builtin_amdgcn_mfma_f32_16x16x32_bf16(a, b, c, 0, 0, 0);
}
__device__ __forceinline__ float fsigm(float x) { return 1.f / (1.f + __expf(-x)); }
__device__ __forceinline__ float ftanh(float x) {
    float e = __expf(2.f * x);
    return (e - 1.f) / (e + 1.f);
}

// LLC-coherent 16B load (bypass L1/L2, fully pipelined). Waits are issued
// separately and carry the dest registers as "+v" deps so MFMAs can't hoist.
#define HL(dst, ptr, OFF) \
    asm volatile("global_load_dwordx4 %0, %1, off offset:%2 sc0 sc1" \
                 : "=v"(dst) : "v"(ptr), "n"(OFF))
#define XL32(dst, ptr) \
    asm volatile("global_load_dword %0, %1, off" : "=v"(dst) : "v"(ptr))
#define XL16(dst, ptr) \
    asm volatile("global_load_ushort %0, %1, off" : "=v"(dst) : "v"(ptr))
#define WAITAV(N, A) \
    asm volatile("s_waitcnt vmcnt(%8)" \
                 : "+v"((A)[0]), "+v"((A)[1]), "+v"((A)[2]), "+v"((A)[3]), \
                   "+v"((A)[4]), "+v"((A)[5]), "+v"((A)[6]), "+v"((A)[7]) \
                 : "n"(N))

// ---------------- prep: x fp32 -> bf16 ----------------
__global__ __launch_bounds__(256) void k_convert_x(const float* __restrict__ x,
                                                   u16* __restrict__ xb, int n4) {
    int i = blockIdx.x * 256 + threadIdx.x;
    int stride = gridDim.x * 256;
    const float4* xv = (const float4*)x;
    u64* ov = (u64*)xb;
    for (; i < n4; i += stride) {
        float4 v = xv[i];
        u64 o = (u64)f2bf(v.x) | ((u64)f2bf(v.y) << 16) |
                ((u64)f2bf(v.z) << 32) | ((u64)f2bf(v.w) << 48);
        ov[i] = o;
    }
}

// ---------------- prep: A[R][C] fp32 -> At[C][R] bf16 (tiled transpose) ----------------
__global__ __launch_bounds__(1024) void k_transpose_bf(const float* __restrict__ A,
                                                       u16* __restrict__ At, int R, int C) {
    __shared__ float tile[32][33];
    int cb = blockIdx.x * 32, rb = blockIdx.y * 32;
    int tx = threadIdx.x, ty = threadIdx.y;
    tile[ty][tx] = A[(size_t)(rb + ty) * C + cb + tx];
    __syncthreads();
    At[(size_t)(cb + ty) * R + rb + tx] = f2bf(tile[tx][ty]);
}

// ---------------- prep: zero h double-buffer + barrier counter ----------------
__global__ __launch_bounds__(256) void k_zero(u64* hb, u32* cnt) {
    int i = blockIdx.x * 256 + threadIdx.x;
    int stride = gridDim.x * 256;
    const int n = 2 * BB * HH * 2 / 8;   // bytes / 8
    for (; i < n; i += stride) hb[i] = 0ull;
    if (blockIdx.x == 0 && threadIdx.x == 0) *cnt = 0u;
}

// ---------------- phase 1: xW = x@W + b  (bf16 MFMA, out row-permuted [s][b][4H]) -----
template <bool XW32>
__global__ __launch_bounds__(256) void k_gemm_xw(const u16* __restrict__ Abf,
                                                 const u16* __restrict__ Bt,
                                                 const float* __restrict__ bias,
                                                 void* __restrict__ xw) {
    __shared__ u16 As[128 * 32];
    __shared__ u16 Bs[128 * 32];
    int bid = blockIdx.x;
    int wid = (bid & 7) * 1024 + (bid >> 3);   // XCD-chunked swizzle
    int mt = wid & 255, nt = wid >> 8;
    size_t rb = (size_t)mt * 128;
    int cb = nt * 128;
    int tid = threadIdx.x;
    int w = tid >> 6, l = tid & 63;
    int lr = l >> 4, lc = l & 15;
    int wr = (w >> 1) * 64, wc = (w & 1) * 64;
    f32x4 acc[4][4] = {};
    for (int kb = 0; kb < II; kb += 32) {
        __syncthreads();
#pragma unroll
        for (int q = 0; q < 2; ++q) {
            int bo = q * 4096 + w * 1024 + l * 16;
            int row = bo >> 6;
            int off = (bo & 63) >> 1;
            const u16* srcA = Abf + (rb + row) * II + kb + off;
            __builtin_amdgcn_global_load_lds((as1_uint_t*)srcA,
                (as3_uint_t*)((char*)As + q * 4096 + w * 1024), 16, 0, 0);
            const u16* srcB = Bt + (size_t)(cb + row) * II + kb + off;
            __builtin_amdgcn_global_load_lds((as1_uint_t*)srcB,
                (as3_uint_t*)((char*)Bs + q * 4096 + w * 1024), 16, 0, 0);
        }
        __syncthreads();
        s16x8 af[4], bf[4];
#pragma unroll
        for (int m = 0; m < 4; ++m)
            af[m] = *(const s16x8*)(As + (wr + m * 16 + lc) * 32 + lr * 8);
#pragma unroll
        for (int n = 0; n < 4; ++n)
            bf[n] = *(const s16x8*)(Bs + (wc + n * 16 + lc) * 32 + lr * 8);
#pragma unroll
        for (int m = 0; m < 4; ++m)
#pragma unroll
            for (int n = 0; n < 4; ++n)
                acc[m][n] = mfma16(af[m], bf[n], acc[m][n]);
    }
    float bv[4];
#pragma unroll
    for (int n = 0; n < 4; ++n) bv[n] = bias[cb + wc + n * 16 + lc];
#pragma unroll
    for (int m = 0; m < 4; ++m) {
#pragma unroll
        for (int r = 0; r < 4; ++r) {
            size_t g = rb + wr + m * 16 + lr * 4 + r;       // global row b*512+s
            size_t srow = ((g & 511) << 6) | (g >> 9);      // s*64 + b
#pragma unroll
            for (int n = 0; n < 4; ++n) {
                float v = acc[m][n][r] + bv[n];
                size_t idx = srow * G4 + cb + wc + n * 16 + lc;
                if (XW32) ((float*)xw)[idx] = v;
                else      ((u16*)xw)[idx] = f2bf(v);
            }
        }
    }
}

// ---------------- phase 2: persistent recurrent kernel -------------------------------
// 64 WGs x 256 thr, 1 WG/CU. WG j owns fused-gate cols {g*1024 + j*16 .. +16}; wave w
// owns batch rows 16w..16w+16. U slice (128 KB) in LDS. h exchange through LLC:
// stores = relaxed agent atomics (write-through), loads = asm global_load sc0 sc1
// (LLC-coherent, pipelined). NO release/acquire fences -> no buffer_wbl2/buffer_inv
// in the loop. Grid barrier = relaxed fetch_add + relaxed poll; ordering comes from
// an explicit s_waitcnt vmcnt(0) drain before the barrier.
template <bool XW32>
__global__ __launch_bounds__(256, 1) void k_lstm3(const u16* __restrict__ Ut,
                                                  const void* __restrict__ xw,
                                                  u16* hb, u32* cnt,
                                                  float* __restrict__ out) {
    __shared__ u16 Us[8192 * 8];   // chunk ch=((kk*4+g)*4+lr)*16+lc -> 8 bf16
    const int j = blockIdx.x;
    const int tid = threadIdx.x;
    const int w = tid >> 6, l = tid & 63;
    const int lr = l >> 4, lc = l & 15;
    const int rowbase = w * 16;
    const int col = j * 16 + lc;

    // ---- stage U slice into LDS (one-time) ----
    for (int i = 0; i < 32; ++i) {
        int ch = tid + (i << 8);
        int lc2 = ch & 15, lr2 = (ch >> 4) & 3, g2 = (ch >> 6) & 3, kk2 = ch >> 8;
        const u16* src = Ut + (size_t)(g2 * HH + j * 16 + lc2) * II + kk2 * 32 + lr2 * 8;
        *(s16x8*)(Us + (size_t)ch * 8) = *(const s16x8*)src;
    }

    float cc[4] = {0.f, 0.f, 0.f, 0.f};
    const size_t xwlane = (size_t)(rowbase + lr * 4) * G4 + col;

    // per-(g,r) prefetch pointers, currently pointing at timestep 1 data
    const char* xwp[16];
#pragma unroll
    for (int g = 0; g < 4; ++g)
#pragma unroll
        for (int r = 0; r < 4; ++r) {
            size_t e = (size_t)BB * G4 + xwlane + (size_t)r * G4 + (size_t)g * HH;
            xwp[g * 4 + r] = (const char*)xw + (XW32 ? e * 4 : e * 2);
        }

    // cur = xw(t=0), plain loads (compiler-managed waits)
    float cur[16];
#pragma unroll
    for (int g = 0; g < 4; ++g)
#pragma unroll
        for (int r = 0; r < 4; ++r) {
            size_t e = xwlane + (size_t)r * G4 + (size_t)g * HH;
            cur[g * 4 + r] = XW32 ? ((const float*)xw)[e] : bf2f(((const u16*)xw)[e]);
        }
    __syncthreads();   // Us ready

    for (int t = 0; t < SS; ++t) {
        // 16 MFMA chains: acc[g][kk&3]; chain 0 carries the xW+b term
        f32x4 acc[4][4];
#pragma unroll
        for (int g = 0; g < 4; ++g) {
#pragma unroll
            for (int r = 0; r < 4; ++r) acc[g][0][r] = cur[g * 4 + r];
            acc[g][1] = f32x4{0.f, 0.f, 0.f, 0.f};
            acc[g][2] = f32x4{0.f, 0.f, 0.f, 0.f};
            acc[g][3] = f32x4{0.f, 0.f, 0.f, 0.f};
        }

        // ---- issue ordered vmem: 32 h-loads (LLC) then 16 xw prefetch ----
        const u16* hrow = hb + (size_t)(t & 1) * (BB * HH) +
                          (size_t)(rowbase + lc) * HH + lr * 8;
        s16x8 av[32];
#pragma unroll
        for (int kk = 0; kk < 32; ++kk) HL(av[kk], hrow, kk * 64);

        u32 nxt[16];
#pragma unroll
        for (int q = 0; q < 16; ++q) {
            if (XW32) { XL32(nxt[q], xwp[q]); }
            else      { XL16(nxt[q], xwp[q]); }
        }

        // ---- 4 phases: wait 8 h-loads, fire 32 MFMAs ----
#pragma unroll
        for (int kb = 0; kb < 4; ++kb) {
            WAITAV(40 - 8 * kb, av + kb * 8);   // (24-8kb) h remaining + 16 xw in flight
#pragma unroll
            for (int u = 0; u < 8; ++u) {
                const int kk = kb * 8 + u;
#pragma unroll
                for (int g = 0; g < 4; ++g) {
                    const s16x8 bv = *(const s16x8*)(Us + (size_t)(((kk * 4 + g) * 4 + lr) * 16 + lc) * 8);
                    acc[g][kk & 3] = mfma16(av[kk], bv, acc[g][kk & 3]);
                }
            }
        }

        // ---- activations, cell update, outputs ----
        u16* hwr = hb + (size_t)((t + 1) & 1) * (BB * HH);
        float hval[4];
#pragma unroll
        for (int r = 0; r < 4; ++r) {
            float gi = (acc[0][0][r] + acc[0][1][r]) + (acc[0][2][r] + acc[0][3][r]);
            float gf = (acc[1][0][r] + acc[1][1][r]) + (acc[1][2][r] + acc[1][3][r]);
            float gg = (acc[2][0][r] + acc[2][1][r]) + (acc[2][2][r] + acc[2][3][r]);
            float go = (acc[3][0][r] + acc[3][1][r]) + (acc[3][2][r] + acc[3][3][r]);
            float i_ = fsigm(gi);
            float f_ = fsigm(gf);
            float g_ = ftanh(gg);
            float o_ = fsigm(go);
            cc[r] = f_ * cc[r] + i_ * g_;
            hval[r] = o_ * ftanh(cc[r]);
        }
#pragma unroll
        for (int r = 0; r < 4; ++r) {
            int row = rowbase + lr * 4 + r;
            out[(size_t)row * (SS * HH) + (size_t)t * HH + col] = hval[r];
            if (t < SS - 1) {
                __hip_atomic_store(hwr + (size_t)row * HH + col, f2bf(hval[r]),
                                   __ATOMIC_RELAXED, __HIP_MEMORY_SCOPE_AGENT);
            } else {
                out[(size_t)(BB * SS * HH) + (size_t)row * HH + col] = hval[r];
                out[(size_t)(BB * SS * HH + BB * HH) + (size_t)row * HH + col] = cc[r];
            }
        }

        if (t < SS - 1) {
            // drain: h stores acked at LLC AND prefetch landed (nxt deps pin consumers)
            asm volatile("s_waitcnt vmcnt(0)"
                         : "+v"(nxt[0]), "+v"(nxt[1]), "+v"(nxt[2]), "+v"(nxt[3]),
                           "+v"(nxt[4]), "+v"(nxt[5]), "+v"(nxt[6]), "+v"(nxt[7]),
                           "+v"(nxt[8]), "+v"(nxt[9]), "+v"(nxt[10]), "+v"(nxt[11]),
                           "+v"(nxt[12]), "+v"(nxt[13]), "+v"(nxt[14]), "+v"(nxt[15]));
            __syncthreads();
            if (tid == 0) {
                u32 target = (u32)(t + 1) * NWG_REC;
                u32 old = __hip_atomic_fetch_add(cnt, 1u, __ATOMIC_RELAXED,
                                                 __HIP_MEMORY_SCOPE_AGENT);
                if (old != target - 1) {
                    while (__hip_atomic_load(cnt, __ATOMIC_RELAXED,
                                             __HIP_MEMORY_SCOPE_AGENT) < target)
                        __builtin_amdgcn_s_sleep(1);
                }
            }
            __syncthreads();
            if (t < SS - 2) {   // advance prefetch pointers (stay in bounds at the tail)
#pragma unroll
                for (int q = 0; q < 16; ++q)
                    xwp[q] += (size_t)BB * G4 * (XW32 ? 4 : 2);
            }
        }
#pragma unroll
        for (int q = 0; q < 16; ++q)
            cur[q] = XW32 ? __uint_as_float(nxt[q]) : __uint_as_float(nxt[q] << 16);
    }
}

// ---------------- host launch ----------------
extern "C" void kernel_launch(void* const* d_in, const int* in_sizes, int n_in,
                              void* d_out, int out_size, void* d_ws, size_t ws_size,
                              hipStream_t stream) {
    const float* x = (const float*)d_in[0];
    const float* W = (const float*)d_in[1];
    const float* U = (const float*)d_in[2];
    const float* b = (const float*)d_in[3];
    float* out = (float*)d_out;

    size_t xb_b  = (size_t)BB * SS * II * 2;   // 64 MiB
    size_t wt_b  = (size_t)G4 * II * 2;        // 8 MiB each
    size_t hb_b  = (size_t)2 * BB * HH * 2;    // 256 KiB
    size_t xw32_b = (size_t)BB * SS * G4 * 4;  // 512 MiB
    size_t xw16_b = xw32_b / 2;
    size_t base = xb_b + 2 * wt_b;

    int mode = (base + xw32_b + hb_b + 256 <= ws_size) ? 0 : 1;

    char* p = (char*)d_ws;
    u16* xb = (u16*)p;
    u16* Wt = (u16*)(p + xb_b);
    u16* Ut = (u16*)(p + xb_b + wt_b);
    char* q = p + base;
    void* xw = (void*)q;
    q += (mode == 0) ? xw32_b : xw16_b;
    u16* hb = (u16*)q; q += hb_b;
    u32* cnt = (u32*)q;

    k_convert_x<<<2048, 256, 0, stream>>>(x, xb, BB * SS * II / 4);
    k_transpose_bf<<<dim3(G4 / 32, II / 32), dim3(32, 32), 0, stream>>>(W, Wt, II, G4);
    k_transpose_bf<<<dim3(G4 / 32, II / 32), dim3(32, 32), 0, stream>>>(U, Ut, II, G4);
    k_zero<<<64, 256, 0, stream>>>((u64*)hb, cnt);

    if (mode == 0) {
        k_gemm_xw<true><<<8192, 256, 0, stream>>>(xb, Wt, b, xw);
        k_lstm3<true><<<NWG_REC, 256, 0, stream>>>(Ut, xw, hb, cnt, out);
    } else {
        k_gemm_xw<false><<<8192, 256, 0, stream>>>(xb, Wt, b, xw);
        k_lstm3<false><<<NWG_REC, 256, 0, stream>>>(Ut, xw, hb, cnt, out);
    }
}

// Round 4
// 5043.534 us; speedup vs baseline: 2.9034x; 1.1275x over previous
//
#include <hip/hip_runtime.h>

// ---------------- problem constants ----------------
#define BB 64      // batch
#define SS 512     // seq len
#define II 1024    // input dim (K for x@W)
#define HH 1024    // hidden
#define G4 4096    // 4*H fused gates
#define NWG_REC 64 // workgroups doing LSTM work (must all be co-resident)
#define NWG_TOT 256 // + clock-keeper spinner WGs

typedef unsigned short u16;
typedef unsigned int u32;
typedef unsigned long long u64;

typedef short s16x8 __attribute__((ext_vector_type(8)));   // 8 bf16 (4 VGPRs) MFMA A/B frag
typedef float f32x4 __attribute__((ext_vector_type(4)));   // MFMA C/D frag

typedef __attribute__((address_space(1))) const u32 as1_uint_t;
typedef __attribute__((address_space(3))) u32 as3_uint_t;

__device__ __forceinline__ u16 f2bf(float f) {   // RNE float->bf16
    u32 x = __float_as_uint(f);
    x += 0x7fffu + ((x >> 16) & 1u);
    return (u16)(x >> 16);
}
__device__ __forceinline__ float bf2f(u16 v) {
    return __uint_as_float(((u32)v) << 16);
}
__device__ __forceinline__ f32x4 mfma16(s16x8 a, s16x8 b, f32x4 c) {
    return __builtin_amdgcn_mfma_f32_16x16x32_bf16(a, b, c, 0, 0, 0);
}
__device__ __forceinline__ float fsigm(float x) { return 1.f / (1.f + __expf(-x)); }
__device__ __forceinline__ float ftanh(float x) {
    float e = __expf(2.f * x);
    return (e - 1.f) / (e + 1.f);
}

// LLC-coherent loads (bypass L1/L2, fully pipelined).
#define HL(dst, ptr, OFF) \
    asm volatile("global_load_dwordx4 %0, %1, off offset:%2 sc0 sc1" \
                 : "=v"(dst) : "v"(ptr), "n"(OFF))
#define XL32(dst, ptr) \
    asm volatile("global_load_dword %0, %1, off" : "=v"(dst) : "v"(ptr))
#define WAITAV(N, A) \
    asm volatile("s_waitcnt vmcnt(%8)" \
                 : "+v"((A)[0]), "+v"((A)[1]), "+v"((A)[2]), "+v"((A)[3]), \
                   "+v"((A)[4]), "+v"((A)[5]), "+v"((A)[6]), "+v"((A)[7]) \
                 : "n"(N))

// ---------------- prep: x fp32 -> bf16 ----------------
__global__ __launch_bounds__(256) void k_convert_x(const float* __restrict__ x,
                                                   u16* __restrict__ xb, int n4) {
    int i = blockIdx.x * 256 + threadIdx.x;
    int stride = gridDim.x * 256;
    const float4* xv = (const float4*)x;
    u64* ov = (u64*)xb;
    for (; i < n4; i += stride) {
        float4 v = xv[i];
        u64 o = (u64)f2bf(v.x) | ((u64)f2bf(v.y) << 16) |
                ((u64)f2bf(v.z) << 32) | ((u64)f2bf(v.w) << 48);
        ov[i] = o;
    }
}

// ---------------- prep: A[R][C] fp32 -> At[C][R] bf16 (tiled transpose) ----------------
__global__ __launch_bounds__(1024) void k_transpose_bf(const float* __restrict__ A,
                                                       u16* __restrict__ At, int R, int C) {
    __shared__ float tile[32][33];
    int cb = blockIdx.x * 32, rb = blockIdx.y * 32;
    int tx = threadIdx.x, ty = threadIdx.y;
    tile[ty][tx] = A[(size_t)(rb + ty) * C + cb + tx];
    __syncthreads();
    At[(size_t)(cb + ty) * R + rb + tx] = f2bf(tile[tx][ty]);
}

// ---------------- prep: zero h double-buffer + barrier counters + done flag -----------
__global__ __launch_bounds__(256) void k_zero(u64* hb, u64* cnt) {
    int i = blockIdx.x * 256 + threadIdx.x;
    int stride = gridDim.x * 256;
    const int n = 2 * BB * HH * 2 / 8;   // h double-buffer bytes / 8
    for (; i < n; i += stride) hb[i] = 0ull;
    if (blockIdx.x == 0 && threadIdx.x < 512) cnt[threadIdx.x] = 0ull;  // 4KB sync area
}

// ---------------- phase 1: xW = x@W + b  (bf16 MFMA, out row-permuted [s][b][4H]) -----
template <bool XW32>
__global__ __launch_bounds__(256) void k_gemm_xw(const u16* __restrict__ Abf,
                                                 const u16* __restrict__ Bt,
                                                 const float* __restrict__ bias,
                                                 void* __restrict__ xw) {
    __shared__ u16 As[128 * 32];
    __shared__ u16 Bs[128 * 32];
    int bid = blockIdx.x;
    int wid = (bid & 7) * 1024 + (bid >> 3);   // XCD-chunked swizzle
    int mt = wid & 255, nt = wid >> 8;
    size_t rb = (size_t)mt * 128;
    int cb = nt * 128;
    int tid = threadIdx.x;
    int w = tid >> 6, l = tid & 63;
    int lr = l >> 4, lc = l & 15;
    int wr = (w >> 1) * 64, wc = (w & 1) * 64;
    f32x4 acc[4][4] = {};
    for (int kb = 0; kb < II; kb += 32) {
        __syncthreads();
#pragma unroll
        for (int q = 0; q < 2; ++q) {
            int bo = q * 4096 + w * 1024 + l * 16;
            int row = bo >> 6;
            int off = (bo & 63) >> 1;
            const u16* srcA = Abf + (rb + row) * II + kb + off;
            __builtin_amdgcn_global_load_lds((as1_uint_t*)srcA,
                (as3_uint_t*)((char*)As + q * 4096 + w * 1024), 16, 0, 0);
            const u16* srcB = Bt + (size_t)(cb + row) * II + kb + off;
            __builtin_amdgcn_global_load_lds((as1_uint_t*)srcB,
                (as3_uint_t*)((char*)Bs + q * 4096 + w * 1024), 16, 0, 0);
        }
        __syncthreads();
        s16x8 af[4], bf[4];
#pragma unroll
        for (int m = 0; m < 4; ++m)
            af[m] = *(const s16x8*)(As + (wr + m * 16 + lc) * 32 + lr * 8);
#pragma unroll
        for (int n = 0; n < 4; ++n)
            bf[n] = *(const s16x8*)(Bs + (wc + n * 16 + lc) * 32 + lr * 8);
#pragma unroll
        for (int m = 0; m < 4; ++m)
#pragma unroll
            for (int n = 0; n < 4; ++n)
                acc[m][n] = mfma16(af[m], bf[n], acc[m][n]);
    }
    float bv[4];
#pragma unroll
    for (int n = 0; n < 4; ++n) bv[n] = bias[cb + wc + n * 16 + lc];
#pragma unroll
    for (int m = 0; m < 4; ++m) {
#pragma unroll
        for (int r = 0; r < 4; ++r) {
            size_t g = rb + wr + m * 16 + lr * 4 + r;       // global row b*512+s
            size_t srow = ((g & 511) << 6) | (g >> 9);      // s*64 + b
#pragma unroll
            for (int n = 0; n < 4; ++n) {
                float v = acc[m][n][r] + bv[n];
                size_t idx = srow * G4 + cb + wc + n * 16 + lc;
                if (XW32) ((float*)xw)[idx] = v;
                else      ((u16*)xw)[idx] = f2bf(v);
            }
        }
    }
}

// ---------------- phase 2: persistent recurrent kernel -------------------------------
// WGs 0..63: LSTM (1/CU, 128KB LDS). WGs 64..255: clock-keeper spinners (dependent
// FMA chains, poll `done` via sc0sc1 every ~16us, write nothing) — keeps the clock
// governor at high freq while the LSTM WGs sit in sync latency.
// Barrier: 8 split counters (128B apart), fire-and-forget global_atomic_add, detect
// via 8 pipelined sc0sc1 loads. h-stores drain before arrive; out stores overlap poll.
template <bool XW32>
__global__ __launch_bounds__(256, 1) void k_lstm4(const u16* __restrict__ Ut,
                                                  const void* __restrict__ xw,
                                                  u16* hb, u32* cnt,
                                                  float* __restrict__ out) {
    const int j = blockIdx.x;
    const int tid = threadIdx.x;

    if (j >= NWG_REC) {
        // ---- clock-keeper spinner ----
        const u32* dptr = cnt + 512;           // done flag, own cache line
        float a = 1.0f;
        while (true) {
            u32 d;
            asm volatile("global_load_dword %0, %1, off sc0 sc1\n\t"
                         "s_waitcnt vmcnt(0)" : "=v"(d) : "v"(dptr));
            if (d) break;
#pragma unroll 16
            for (int i = 0; i < 4096; ++i)
                asm volatile("v_fmac_f32 %0, %1, %2" : "+v"(a) : "v"(1.0000001f), "v"(a));
        }
        asm volatile("" :: "v"(a));
        return;
    }

    __shared__ u16 Us[8192 * 8];   // chunk ch=((kk*4+g)*4+lr)*16+lc -> 8 bf16
    const int w = tid >> 6, l = tid & 63;
    const int lr = l >> 4, lc = l & 15;
    const int rowbase = w * 16;
    const int col = j * 16 + lc;

    // ---- stage U slice into LDS (one-time) ----
    for (int i = 0; i < 32; ++i) {
        int ch = tid + (i << 8);
        int lc2 = ch & 15, lr2 = (ch >> 4) & 3, g2 = (ch >> 6) & 3, kk2 = ch >> 8;
        const u16* src = Ut + (size_t)(g2 * HH + j * 16 + lc2) * II + kk2 * 32 + lr2 * 8;
        *(s16x8*)(Us + (size_t)ch * 8) = *(const s16x8*)src;
    }

    float cc[4] = {0.f, 0.f, 0.f, 0.f};
    const size_t xwlane = (size_t)(rowbase + lr * 4) * G4 + col;

    const char* xwp[16];
#pragma unroll
    for (int g = 0; g < 4; ++g)
#pragma unroll
        for (int r = 0; r < 4; ++r) {
            size_t e = (size_t)BB * G4 + xwlane + (size_t)r * G4 + (size_t)g * HH;
            xwp[g * 4 + r] = (const char*)xw + (XW32 ? e * 4 : e * 2);
        }

    float cur[16];
#pragma unroll
    for (int g = 0; g < 4; ++g)
#pragma unroll
        for (int r = 0; r < 4; ++r) {
            size_t e = xwlane + (size_t)r * G4 + (size_t)g * HH;
            cur[g * 4 + r] = XW32 ? ((const float*)xw)[e] : bf2f(((const u16*)xw)[e]);
        }

    u32* mycnt = cnt + (size_t)(j & 7) * 32;   // this WG's arrive counter (128B apart)
    __syncthreads();   // Us ready

    for (int t = 0; t < SS; ++t) {
        f32x4 acc[4][4];
#pragma unroll
        for (int g = 0; g < 4; ++g) {
#pragma unroll
            for (int r = 0; r < 4; ++r) acc[g][0][r] = cur[g * 4 + r];
            acc[g][1] = f32x4{0.f, 0.f, 0.f, 0.f};
            acc[g][2] = f32x4{0.f, 0.f, 0.f, 0.f};
            acc[g][3] = f32x4{0.f, 0.f, 0.f, 0.f};
        }

        // ---- issue ordered vmem: 32 h-loads (LLC) then 16 xw prefetch ----
        const u16* hrow = hb + (size_t)(t & 1) * (BB * HH) +
                          (size_t)(rowbase + lc) * HH + lr * 8;
        s16x8 av[32];
#pragma unroll
        for (int kk = 0; kk < 32; ++kk) HL(av[kk], hrow, kk * 64);

        u32 nxt[16];
#pragma unroll
        for (int q = 0; q < 16; ++q) {
            if (XW32) { XL32(nxt[q], xwp[q]); }
            else {
                asm volatile("global_load_ushort %0, %1, off" : "=v"(nxt[q]) : "v"(xwp[q]));
            }
        }

        // ---- 4 phases: wait next 8 h-loads, fire 32 MFMAs ----
        // steady state outstanding at top: [16 out-st(prev)] + 32 hL + 16 xwL = 64
        // vmcnt(40-8kb) waits for out-stores(prev) + h[0..8(kb+1)-1]  (in-order retire)
#pragma unroll
        for (int kb = 0; kb < 4; ++kb) {
            WAITAV(40 - 8 * kb, av + kb * 8);
#pragma unroll
            for (int u = 0; u < 8; ++u) {
                const int kk = kb * 8 + u;
#pragma unroll
                for (int g = 0; g < 4; ++g) {
                    const s16x8 bv = *(const s16x8*)(Us + (size_t)(((kk * 4 + g) * 4 + lr) * 16 + lc) * 8);
                    acc[g][kk & 3] = mfma16(av[kk], bv, acc[g][kk & 3]);
                }
            }
        }

        // ---- activations, cell update ----
        float hval[4];
#pragma unroll
        for (int r = 0; r < 4; ++r) {
            float gi = (acc[0][0][r] + acc[0][1][r]) + (acc[0][2][r] + acc[0][3][r]);
            float gf = (acc[1][0][r] + acc[1][1][r]) + (acc[1][2][r] + acc[1][3][r]);
            float gg = (acc[2][0][r] + acc[2][1][r]) + (acc[2][2][r] + acc[2][3][r]);
            float go = (acc[3][0][r] + acc[3][1][r]) + (acc[3][2][r] + acc[3][3][r]);
            float i_ = fsigm(gi);
            float f_ = fsigm(gf);
            float g_ = ftanh(gg);
            float o_ = fsigm(go);
            cc[r] = f_ * cc[r] + i_ * g_;
            hval[r] = o_ * ftanh(cc[r]);
        }

        if (t < SS - 1) {
            // h stores FIRST, drain, arrive; out stores overlap the poll
            u16* hwr = hb + (size_t)((t + 1) & 1) * (BB * HH);
#pragma unroll
            for (int r = 0; r < 4; ++r) {
                int row = rowbase + lr * 4 + r;
                __hip_atomic_store(hwr + (size_t)row * HH + col, f2bf(hval[r]),
                                   __ATOMIC_RELAXED, __HIP_MEMORY_SCOPE_AGENT);
            }
            asm volatile("s_waitcnt vmcnt(0)"
                         : "+v"(nxt[0]), "+v"(nxt[1]), "+v"(nxt[2]), "+v"(nxt[3]),
                           "+v"(nxt[4]), "+v"(nxt[5]), "+v"(nxt[6]), "+v"(nxt[7]),
                           "+v"(nxt[8]), "+v"(nxt[9]), "+v"(nxt[10]), "+v"(nxt[11]),
                           "+v"(nxt[12]), "+v"(nxt[13]), "+v"(nxt[14]), "+v"(nxt[15])
                         :: "memory");
            __syncthreads();   // all 4 waves' h-stores acked at LLC
            if (tid == 0) {    // fire-and-forget arrive (no return value)
                u32 one = 1u;
                asm volatile("global_atomic_add %0, %1, off"
                             :: "v"(mycnt), "v"(one) : "memory");
            }
#pragma unroll
            for (int r = 0; r < 4; ++r) {   // out stores drain during the poll
                int row = rowbase + lr * 4 + r;
                out[(size_t)row * (SS * HH) + (size_t)t * HH + col] = hval[r];
            }
            if (tid == 0) {
                u32 tgt = (u32)(t + 1) * 8u;
                while (true) {
                    u32 c0, c1, c2, c3, c4, c5, c6, c7;
                    asm volatile(
                        "global_load_dword %0, %8, off sc0 sc1\n\t"
                        "global_load_dword %1, %8, off offset:128 sc0 sc1\n\t"
                        "global_load_dword %2, %8, off offset:256 sc0 sc1\n\t"
                        "global_load_dword %3, %8, off offset:384 sc0 sc1\n\t"
                        "global_load_dword %4, %8, off offset:512 sc0 sc1\n\t"
                        "global_load_dword %5, %8, off offset:640 sc0 sc1\n\t"
                        "global_load_dword %6, %8, off offset:768 sc0 sc1\n\t"
                        "global_load_dword %7, %8, off offset:896 sc0 sc1\n\t"
                        "s_waitcnt vmcnt(0)"
                        : "=v"(c0), "=v"(c1), "=v"(c2), "=v"(c3),
                          "=v"(c4), "=v"(c5), "=v"(c6), "=v"(c7)
                        : "v"(cnt));
                    if (c0 >= tgt && c1 >= tgt && c2 >= tgt && c3 >= tgt &&
                        c4 >= tgt && c5 >= tgt && c6 >= tgt && c7 >= tgt) break;
                    __builtin_amdgcn_s_sleep(1);
                }
            }
            __syncthreads();
            if (t < SS - 2) {
#pragma unroll
                for (int q = 0; q < 16; ++q)
                    xwp[q] += (size_t)BB * G4 * (XW32 ? 4 : 2);
            }
        } else {
            // final step: hidden_seq slice + h_t + c_t
#pragma unroll
            for (int r = 0; r < 4; ++r) {
                int row = rowbase + lr * 4 + r;
                out[(size_t)row * (SS * HH) + (size_t)t * HH + col] = hval[r];
                out[(size_t)(BB * SS * HH) + (size_t)row * HH + col] = hval[r];
                out[(size_t)(BB * SS * HH + BB * HH) + (size_t)row * HH + col] = cc[r];
            }
            if (j == 0 && tid == 0) {   // release the spinners
                __hip_atomic_store(cnt + 512, 1u, __ATOMIC_RELAXED,
                                   __HIP_MEMORY_SCOPE_AGENT);
            }
        }
#pragma unroll
        for (int q = 0; q < 16; ++q)
            cur[q] = XW32 ? __uint_as_float(nxt[q]) : __uint_as_float(nxt[q] << 16);
    }
}

// ---------------- host launch ----------------
extern "C" void kernel_launch(void* const* d_in, const int* in_sizes, int n_in,
                              void* d_out, int out_size, void* d_ws, size_t ws_size,
                              hipStream_t stream) {
    const float* x = (const float*)d_in[0];
    const float* W = (const float*)d_in[1];
    const float* U = (const float*)d_in[2];
    const float* b = (const float*)d_in[3];
    float* out = (float*)d_out;

    size_t xb_b  = (size_t)BB * SS * II * 2;   // 64 MiB
    size_t wt_b  = (size_t)G4 * II * 2;        // 8 MiB each
    size_t hb_b  = (size_t)2 * BB * HH * 2;    // 256 KiB
    size_t xw32_b = (size_t)BB * SS * G4 * 4;  // 512 MiB
    size_t xw16_b = xw32_b / 2;
    size_t base = xb_b + 2 * wt_b;

    int mode = (base + xw32_b + hb_b + 4096 <= ws_size) ? 0 : 1;

    char* p = (char*)d_ws;
    u16* xb = (u16*)p;
    u16* Wt = (u16*)(p + xb_b);
    u16* Ut = (u16*)(p + xb_b + wt_b);
    char* q = p + base;
    void* xw = (void*)q;
    q += (mode == 0) ? xw32_b : xw16_b;
    u16* hb = (u16*)q; q += hb_b;
    u32* cnt = (u32*)q;   // 4KB: 8 counters @128B + done flag @2048B

    k_convert_x<<<2048, 256, 0, stream>>>(x, xb, BB * SS * II / 4);
    k_transpose_bf<<<dim3(G4 / 32, II / 32), dim3(32, 32), 0, stream>>>(W, Wt, II, G4);
    k_transpose_bf<<<dim3(G4 / 32, II / 32), dim3(32, 32), 0, stream>>>(U, Ut, II, G4);
    k_zero<<<64, 256, 0, stream>>>((u64*)hb, (u64*)cnt);

    if (mode == 0) {
        k_gemm_xw<true><<<8192, 256, 0, stream>>>(xb, Wt, b, xw);
        k_lstm4<true><<<NWG_TOT, 256, 0, stream>>>(Ut, xw, hb, cnt, out);
    } else {
        k_gemm_xw<false><<<8192, 256, 0, stream>>>(xb, Wt, b, xw);
        k_lstm4<false><<<NWG_TOT, 256, 0, stream>>>(Ut, xw, hb, cnt, out);
    }
}